// Round 12
// baseline (2006.845 us; speedup 1.0000x reference)
//
#include <hip/hip_runtime.h>
#include <hip/hip_bf16.h>
#include <math.h>

#define M_ROWS 32768   // B*P
#define GB 128         // graphs
#define GP 256         // points per graph

typedef __hip_bfloat16 bf16;
typedef __attribute__((ext_vector_type(8))) short short8;
typedef __attribute__((ext_vector_type(4))) float f32x4;

// ---------------------------------------------------------------------------
__global__ void diag_kernel(float* out, float v) { out[0] = v; }

// ---------------------------------------------------------------------------
// MFMA GEMM, m97 structure. GRID CONVENTION: blockIdx.x = COL tile (N/128),
// blockIdx.y = ROW tile (M/128). x-major dispatch makes consecutive blocks
// share the same A row-panel -> A fetched once to L2/L3 instead of Nt times
// (A=340MB for mid GEMM > L3, so ordering is worth ~4-8x A-traffic).
// MODE 0: cols<64 -> hbuf bf16 [M,64]; cols 64..71 -> sbuf f32 [M,8]
// MODE 1: out bf16 [M,ldc], bias+relu
// MODE 2: out f32 [M,ldc] += (accumulate, no bias)
// MODE 3: out f32 [M,ldc] = v + bias (one-shot mid)
// ---------------------------------------------------------------------------
template<int MODE>
__global__ __launch_bounds__(256) void mgemm(
    const bf16* __restrict__ A1, int lda1,
    const bf16* __restrict__ A2, int lda2, int splitTile,
    const bf16* __restrict__ Wt,              // [N, K] bf16 (W^T) row-major
    const float* __restrict__ bias,           // [N] f32 (unused MODE2)
    float* __restrict__ out0, int ldc,
    float* __restrict__ out1,                 // MODE0: sbuf
    int K)
{
    __shared__ unsigned short Alds[128][64];
    __shared__ unsigned short Blds[128][64];
    const int tid = threadIdx.x;
    const int l = tid & 63;
    const int w = tid >> 6;
    const int wr = w >> 1, wc = w & 1;
    const int rowBase = blockIdx.y * 128;     // row tile (M)
    const int colBase = blockIdx.x * 128;     // col tile (N)

    const int lr = l >> 3;          // 0..7
    const int lc = (l & 7) * 8;     // 0..56
    const int arow = rowBase + w * 32 + lr;
    const bf16* A1b = A1 + (size_t)arow * lda1 + lc;
    const bf16* A2b = A2 ? (A2 + (size_t)arow * lda2 + lc) : A1b;
    const bf16* Bb  = Wt + (size_t)(colBase + w * 32 + lr) * K + lc;

    f32x4 acc[4][4];
    #pragma unroll
    for (int m = 0; m < 4; ++m)
        #pragma unroll
        for (int n = 0; n < 4; ++n)
            acc[m][n] = (f32x4){0.f, 0.f, 0.f, 0.f};

    const int nt = K >> 6;
    for (int t = 0; t < nt; ++t) {
        const bf16* bp; int ldsel; int ko;
        if (t < splitTile) { bp = A1b; ldsel = lda1; ko = t << 6; }
        else               { bp = A2b; ldsel = lda2; ko = (t - splitTile) << 6; }
        const int kb = t << 6;
        __syncthreads();
        #pragma unroll
        for (int j = 0; j < 4; ++j) {
            __builtin_amdgcn_global_load_lds(
                (const __attribute__((address_space(1))) void*)(bp + (size_t)(j * 8) * ldsel + ko),
                (__attribute__((address_space(3))) void*)&Alds[w * 32 + j * 8][0],
                16, 0, 0);
            __builtin_amdgcn_global_load_lds(
                (const __attribute__((address_space(1))) void*)(Bb + (size_t)(j * 8) * K + kb),
                (__attribute__((address_space(3))) void*)&Blds[w * 32 + j * 8][0],
                16, 0, 0);
        }
        __syncthreads();
        #pragma unroll
        for (int kk = 0; kk < 2; ++kk) {
            const int co = kk * 32 + (l >> 4) * 8;
            short8 a[4], b[4];
            #pragma unroll
            for (int m = 0; m < 4; ++m)
                a[m] = *(const short8*)&Alds[wr * 64 + m * 16 + (l & 15)][co];
            #pragma unroll
            for (int n = 0; n < 4; ++n)
                b[n] = *(const short8*)&Blds[wc * 64 + n * 16 + (l & 15)][co];
            #pragma unroll
            for (int m = 0; m < 4; ++m)
                #pragma unroll
                for (int n = 0; n < 4; ++n)
                    acc[m][n] = __builtin_amdgcn_mfma_f32_16x16x32_bf16(
                        a[m], b[n], acc[m][n], 0, 0, 0);
        }
    }

    // epilogue: C/D layout col=lane&15, row=(lane>>4)*4+reg  [m89/m91]
    const int r0 = rowBase + wr * 64 + (l >> 4) * 4;
    const int c0 = colBase + wc * 64 + (l & 15);
    #pragma unroll
    for (int m = 0; m < 4; ++m) {
        #pragma unroll
        for (int n = 0; n < 4; ++n) {
            const int col = c0 + n * 16;
            const float bv = (MODE == 2) ? 0.f : bias[col];
            #pragma unroll
            for (int g = 0; g < 4; ++g) {
                const int row = r0 + m * 16 + g;
                float v = acc[m][n][g] + bv;
                if (MODE == 0) {
                    if (col < 64)
                        ((bf16*)out0)[(size_t)row * 64 + col] = __float2bfloat16(v);
                    else if (col < 72)
                        out1[(size_t)row * 8 + (col - 64)] = v;
                } else if (MODE == 1) {
                    ((bf16*)out0)[(size_t)row * ldc + col] =
                        __float2bfloat16(fmaxf(v, 0.f));
                } else if (MODE == 2) {
                    out0[(size_t)row * ldc + col] += v;
                } else {
                    out0[(size_t)row * ldc + col] = v;
                }
            }
        }
    }
}

// ---------------------------------------------------------------------------
// Fused Wo prep for all 8 layers. grid (36, 32, 8); guards trim.
// ---------------------------------------------------------------------------
struct WoArgs { const float* Wo[8]; };
__global__ __launch_bounds__(256) void wprep_t_all(
    WoArgs a, bf16* __restrict__ wtoBase, int bigFlag)
{
    const int fi_[8]   = {8, 256, 256, 512, 512, 512, 1024, 1024};
    const int fip_[8]  = {64, 256, 256, 512, 512, 512, 1024, 1024};
    const int fo_[8]   = {256, 256, 512, 512, 512, 1024, 1024, 1024};
    const int Ko_[8]   = {192, 384, 384, 640, 640, 640, 1152, 1152};
    const size_t ofs_[8] = {0, 49152, 147456, 344064, 671744, 999424,
                            1654784, 2834432};
    const int L = blockIdx.z;
    const int Kpad = Ko_[L], N = fo_[L];
    const int k_t = blockIdx.x * 32, n_t = blockIdx.y * 32;
    if (k_t >= Kpad || n_t >= N) return;
    const int fiReal = fi_[L];
    const int fiPad = bigFlag ? fip_[L] : fi_[L];
    const float* W = a.Wo[L];
    bf16* Wt = wtoBase + ofs_[L];

    __shared__ float tl[32][33];
    const int tx = threadIdx.x, ty = threadIdx.y;
    #pragma unroll
    for (int j = 0; j < 4; ++j) {
        int k = k_t + ty + j * 8;
        int s = (k < fiReal) ? k : ((k >= fiPad) ? (k - fiPad + fiReal) : -1);
        float v = 0.f;
        if (s >= 0 && s < fiReal + 128) v = W[(size_t)s * N + n_t + tx];
        tl[ty + j * 8][tx] = v;
    }
    __syncthreads();
    #pragma unroll
    for (int j = 0; j < 4; ++j) {
        int n = n_t + ty + j * 8;
        Wt[(size_t)n * Kpad + k_t + tx] = __float2bfloat16(tl[tx][ty + j * 8]);
    }
}

// ---------------------------------------------------------------------------
// Fused W_sh prep for all 8 layers. grid (4, 128, 8).
// ---------------------------------------------------------------------------
struct ShArgs { const float* Wh[8]; const float* Ws[8]; };
__global__ __launch_bounds__(256) void wprep_sh_all(
    ShArgs a, bf16* __restrict__ wshBase)
{
    const int fi_[8] = {8, 256, 256, 512, 512, 512, 1024, 1024};
    const int Kh_[8] = {64, 256, 256, 512, 512, 512, 1024, 1024};
    const size_t ofs_[8] = {0, 8192, 40960, 73728, 139264, 204800,
                            270336, 401408};
    const int L = blockIdx.z;
    const int Khpad = Kh_[L];
    const int k = blockIdx.x * 256 + threadIdx.x;
    if (k >= Khpad) return;
    const int n = blockIdx.y;
    const int fi = fi_[L];
    float v = 0.f;
    if (k < fi) {
        if (n < 64) v = a.Wh[L][(size_t)k * 64 + n];
        else if (n < 68) {
            v = __bfloat162float(__float2bfloat16(a.Ws[L][(size_t)k * 4 + (n - 64)]));
        } else if (n < 72) {
            float wv = a.Ws[L][(size_t)k * 4 + (n - 68)];
            float hi = __bfloat162float(__float2bfloat16(wv));
            v = wv - hi;
        }
    }
    (wshBase + ofs_[L])[(size_t)n * Khpad + k] = __float2bfloat16(v);
}

// ---------------------------------------------------------------------------
// Segmented W_mid prep (small path). grid (162,16).
// ---------------------------------------------------------------------------
__global__ __launch_bounds__(256) void wprep_mid_all(
    const float* __restrict__ W_mid, bf16* __restrict__ wtm0)
{
    const int segBlkStart[10] = {0, 2, 10, 18, 34, 50, 66, 98, 130, 162};
    const int segKm[9]   = {64, 256, 256, 512, 512, 512, 1024, 1024, 1024};
    const int segKr[9]   = {8, 256, 256, 512, 512, 512, 1024, 1024, 1024};
    const int segMrow[9] = {0, 8, 264, 520, 1032, 1544, 2056, 3080, 4104};
    const int segWOff[9] = {0, 32768, 163840, 294912, 557056, 819200,
                            1081344, 1605632, 2129920};
    __shared__ float tl[32][33];
    int bx = blockIdx.x;
    int seg = 0;
    while (bx >= segBlkStart[seg + 1]) ++seg;
    const int kb = bx - segBlkStart[seg];
    const float* W = W_mid + (size_t)segMrow[seg] * 512;
    bf16* Wt = wtm0 + segWOff[seg];
    const int K = segKr[seg], Kpad = segKm[seg];
    const int tx = threadIdx.x, ty = threadIdx.y;
    const int k_t = kb * 32, n_t = blockIdx.y * 32;
    #pragma unroll
    for (int j = 0; j < 4; ++j) {
        int k = k_t + ty + j * 8;
        tl[ty + j * 8][tx] = (k < K) ? W[(size_t)k * 512 + n_t + tx] : 0.f;
    }
    __syncthreads();
    #pragma unroll
    for (int j = 0; j < 4; ++j) {
        int n = n_t + ty + j * 8;
        Wt[(size_t)n * Kpad + k_t + tx] = __float2bfloat16(tl[tx][ty + j * 8]);
    }
}

// ---------------------------------------------------------------------------
// One-shot W_mid prep (big path): Wt [512, 5184] bf16. grid (162,16).
// ---------------------------------------------------------------------------
__global__ __launch_bounds__(256) void wprep_mid_big(
    const float* __restrict__ W_mid, bf16* __restrict__ Wt)
{
    const int off_[9]  = {0, 64, 320, 576, 1088, 1600, 2112, 3136, 4160};
    const int size_[9] = {8, 256, 256, 512, 512, 512, 1024, 1024, 1024};
    const int mrow_[9] = {0, 8, 264, 520, 1032, 1544, 2056, 3080, 4104};
    __shared__ float tl[32][33];
    const int tx = threadIdx.x, ty = threadIdx.y;
    const int k_t = blockIdx.x * 32, n_t = blockIdx.y * 32;
    #pragma unroll
    for (int j = 0; j < 4; ++j) {
        int k = k_t + ty + j * 8;
        int s = -1;
        #pragma unroll
        for (int g = 0; g < 9; ++g)
            if (k >= off_[g] && k < off_[g] + size_[g]) s = mrow_[g] + (k - off_[g]);
        tl[ty + j * 8][tx] = (s >= 0) ? W_mid[(size_t)s * 512 + n_t + tx] : 0.f;
    }
    __syncthreads();
    #pragma unroll
    for (int j = 0; j < 4; ++j) {
        int n = n_t + ty + j * 8;
        Wt[(size_t)n * 5184 + k_t + tx] = __float2bfloat16(tl[tx][ty + j * 8]);
    }
}

struct BiasArgs { const float* bh[8]; const float* bs[8]; };
__global__ __launch_bounds__(128) void bias_build_all(
    BiasArgs a, float* __restrict__ out)
{
    const int L = blockIdx.x, t = threadIdx.x;
    out[L * 128 + t] = (t < 64) ? a.bh[L][t] : (t < 68 ? a.bs[L][t - 64] : 0.f);
}

// ---------------------------------------------------------------------------
__global__ __launch_bounds__(256) void f2b_pad(const float* __restrict__ in,
                                               bf16* __restrict__ out)
{
    int i = blockIdx.x * 256 + threadIdx.x;
    int row = i >> 3, c = i & 7;
    out[(size_t)row * 192 + c] = __float2bfloat16(in[i]);
}

__global__ __launch_bounds__(256) void f2b_big(const float* __restrict__ in,
                                               bf16* __restrict__ feat)
{
    int i = blockIdx.x * 256 + threadIdx.x;   // M*64
    int row = i >> 6, c = i & 63;
    feat[(size_t)row * 5184 + c] =
        __float2bfloat16(c < 8 ? in[row * 8 + c] : 0.f);
}

// ---------------------------------------------------------------------------
// Wave-64 integer min reduce via DPP (VALU pipe), broadcast via readlane(63).
// ---------------------------------------------------------------------------
__device__ __forceinline__ int wave_imin_bcast(int x)
{
    int y;
    y = __builtin_amdgcn_update_dpp(x, x, 0x111, 0xf, 0xf, false); x = y < x ? y : x;
    y = __builtin_amdgcn_update_dpp(x, x, 0x112, 0xf, 0xf, false); x = y < x ? y : x;
    y = __builtin_amdgcn_update_dpp(x, x, 0x114, 0xf, 0xf, false); x = y < x ? y : x;
    y = __builtin_amdgcn_update_dpp(x, x, 0x118, 0xf, 0xf, false); x = y < x ? y : x;
    y = __builtin_amdgcn_update_dpp(x, x, 0x142, 0xf, 0xf, false); x = y < x ? y : x;
    y = __builtin_amdgcn_update_dpp(x, x, 0x143, 0xf, 0xf, false); x = y < x ? y : x;
    return __builtin_amdgcn_readlane(x, 63);
}

// ---------------------------------------------------------------------------
// Fused kNN + gather. 4 waves/block = 4 points; grid M/4.
// ---------------------------------------------------------------------------
__global__ __launch_bounds__(256) void knng_kernel(
    const float* __restrict__ sbuf,   // [B*P, 8] (hi/lo split)
    const bf16* __restrict__ h,       // [B*P, 64]
    bf16* __restrict__ xtgt, int stride, int fiL, int padN)
{
    __shared__ float ss[GP][5];
    __shared__ int   qsh[4][20];
    __shared__ float wvs[4][20];
    const int t = threadIdx.x;
    const int b = blockIdx.x >> 6;
    {
        const float4 v1 = ((const float4*)(sbuf + ((size_t)b * GP + t) * 8))[0];
        const float4 v2 = ((const float4*)(sbuf + ((size_t)b * GP + t) * 8))[1];
        float ax = v1.x + v2.x, ay = v1.y + v2.y,
              az = v1.z + v2.z, aw = v1.w + v2.w;
        ss[t][0] = ax; ss[t][1] = ay; ss[t][2] = az; ss[t][3] = aw;
        ss[t][4] = ax * ax + ay * ay + az * az + aw * aw;
    }
    __syncthreads();

    const int w = t >> 6, l = t & 63;
    const int pt = blockIdx.x * 4 + w;          // global point id
    const int p = pt & 255;                     // local point id
    const float px = ss[p][0], py = ss[p][1], pz = ss[p][2], pq = ss[p][3];
    const float psq = ss[p][4];

    float d0, d1, d2, d3; int q0, q1, q2, q3;
    #define KNN_DIST(DD, QQ, J) { \
        const int q_ = l + (J) * 64; \
        float dot_ = px * ss[q_][0] + py * ss[q_][1] \
                   + pz * ss[q_][2] + pq * ss[q_][3]; \
        DD = fmaxf(psq + ss[q_][4] - 2.f * dot_, 0.f); QQ = q_; }
    KNN_DIST(d0, q0, 0) KNN_DIST(d1, q1, 1)
    KNN_DIST(d2, q2, 2) KNN_DIST(d3, q3, 3)
    #undef KNN_DIST
    #define KNN_CE(DA, DB, QA, QB) { \
        if (DA > DB) { float td = DA; DA = DB; DB = td; \
                       int tq = QA; QA = QB; QB = tq; } }
    KNN_CE(d0, d1, q0, q1) KNN_CE(d2, d3, q2, q3)
    KNN_CE(d0, d2, q0, q2) KNN_CE(d1, d3, q1, q3)
    KNN_CE(d1, d2, q1, q2)
    #undef KNN_CE

    float outd = 0.f; int outq = 0;
    #pragma unroll
    for (int k = 0; k < 20; ++k) {
        const int mb = wave_imin_bcast(__float_as_int(d0));
        unsigned long long msk = __ballot(__float_as_int(d0) == mb);
        const int winner = __ffsll((long long)msk) - 1;
        const int qwin = __builtin_amdgcn_readlane(q0, winner);
        if (l == k) { outd = __int_as_float(mb); outq = qwin; }
        const bool pop = (l == winner);
        d0 = pop ? d1 : d0; q0 = pop ? q1 : q0;
        d1 = pop ? d2 : d1; q1 = pop ? q2 : q1;
        d2 = pop ? d3 : d2; q2 = pop ? q3 : q2;
        d3 = pop ? 3.402823466e38f : d3;
    }
    if (l < 20) {
        qsh[w][l] = outq;
        wvs[w][l] = expf(-10.f * outd);
    }
    __syncthreads();

    // gather: lane = feature, LDS same-address broadcast for (q, w)
    float sum = 0.f, mx = -3.402823466e38f;
    #pragma unroll 4
    for (int k = 0; k < 20; ++k) {
        const int q = qsh[w][k];
        const float wv = wvs[w][k];
        float val = __bfloat162float(h[(((size_t)b << 8) + q) * 64 + l]) * wv;
        sum += val;
        mx = fmaxf(mx, val);
    }
    bf16* out = xtgt + (size_t)pt * stride + fiL;
    out[l] = __float2bfloat16(sum * (1.f / 20.f));
    out[64 + l] = __float2bfloat16(mx);
    if (l < padN) out[128 + l] = __float2bfloat16(0.f);
}

// ---------------------------------------------------------------------------
__global__ __launch_bounds__(256) void init_mid(float* __restrict__ mid,
                                                const float* __restrict__ b_mid)
{
    size_t i = (size_t)blockIdx.x * 256 + threadIdx.x;
    mid[i] = b_mid[i & 511];
}

// ---------------------------------------------------------------------------
// Multi-pool (min,max,mean,sum,std,median-lower); median via bitonic sort.
// ---------------------------------------------------------------------------
__global__ __launch_bounds__(256) void pool_kernel(
    const float* __restrict__ mid, float* __restrict__ pooled)
{
    __shared__ float tile[GP][33];
    __shared__ float rbuf[256];
    const int b = blockIdx.x;
    const int c0 = blockIdx.y * 32;
    const int t = threadIdx.x;

    #pragma unroll 8
    for (int l = 0; l < 32; ++l) {
        int lin = l * 256 + t;
        int row = lin >> 5;
        int col = lin & 31;
        tile[row][col] = mid[((size_t)b * GP + row) * 512 + c0 + col];
    }
    __syncthreads();

    const int col = t & 31, g = t >> 5;
    float mn = 3.402823466e38f, mx = -3.402823466e38f, sm = 0.f, s2 = 0.f;
    for (int r = g * 32; r < g * 32 + 32; ++r) {
        float v = tile[r][col];
        mn = fminf(mn, v); mx = fmaxf(mx, v); sm += v; s2 += v * v;
    }
    float* outb = pooled + (size_t)b * 3072 + c0;

    rbuf[t] = mn; __syncthreads();
    if (t < 32) {
        float v = rbuf[t];
        #pragma unroll
        for (int k = 1; k < 8; ++k) v = fminf(v, rbuf[t + 32 * k]);
        outb[0 * 512 + t] = v;
    }
    __syncthreads();
    rbuf[t] = mx; __syncthreads();
    if (t < 32) {
        float v = rbuf[t];
        #pragma unroll
        for (int k = 1; k < 8; ++k) v = fmaxf(v, rbuf[t + 32 * k]);
        outb[1 * 512 + t] = v;
    }
    __syncthreads();
    rbuf[t] = sm; __syncthreads();
    float meanv = 0.f;
    if (t < 32) {
        float v = 0.f;
        #pragma unroll
        for (int k = 0; k < 8; ++k) v += rbuf[t + 32 * k];
        meanv = v * (1.f / 256.f);
        outb[2 * 512 + t] = meanv;
        outb[3 * 512 + t] = v;
    }
    __syncthreads();
    rbuf[t] = s2; __syncthreads();
    if (t < 32) {
        float v = 0.f;
        #pragma unroll
        for (int k = 0; k < 8; ++k) v += rbuf[t + 32 * k];
        float var = v * (1.f / 256.f) - meanv * meanv;
        outb[4 * 512 + t] = sqrtf(fmaxf(var, 0.f) + 1e-5f);
    }

    for (int size = 2; size <= 256; size <<= 1) {
        for (int stride = size >> 1; stride > 0; stride >>= 1) {
            __syncthreads();
            #pragma unroll
            for (int it = 0; it < 16; ++it) {
                int task = it * 256 + t;
                int c = task & 31;
                int pp = task >> 5;
                int i = 2 * pp - (pp & (stride - 1));
                int j = i + stride;
                bool up = ((i & size) == 0);
                float va = tile[i][c], vb = tile[j][c];
                bool sw = up ? (va > vb) : (va < vb);
                if (sw) { tile[i][c] = vb; tile[j][c] = va; }
            }
        }
    }
    __syncthreads();
    if (t < 32) outb[5 * 512 + t] = tile[127][t];
}

// ---------------------------------------------------------------------------
__global__ __launch_bounds__(128) void head_kernel(
    const float* __restrict__ pooled, const float* __restrict__ Wh,
    const float* __restrict__ bh, float* __restrict__ out)
{
    __shared__ float sh[3072];
    const int b = blockIdx.x, t = threadIdx.x;
    for (int l = t; l < 3072; l += 128) sh[l] = pooled[(size_t)b * 3072 + l];
    __syncthreads();
    float acc = bh[t];
    for (int k = 0; k < 3072; ++k) acc += sh[k] * Wh[(size_t)k * 128 + t];
    out[(size_t)b * 128 + t] = acc;
}

// ---------------------------------------------------------------------------
extern "C" void kernel_launch(void* const* d_in, const int* in_sizes, int n_in,
                              void* d_out, int out_size, void* d_ws, size_t ws_size,
                              hipStream_t stream)
{
    const int fi[8]  = {8, 256, 256, 512, 512, 512, 1024, 1024};
    const int fip[8] = {64, 256, 256, 512, 512, 512, 1024, 1024};
    const int fo[8]  = {256, 256, 512, 512, 512, 1024, 1024, 1024};
    const int Kh[8]  = {64, 256, 256, 512, 512, 512, 1024, 1024};
    const int Ko[8]  = {192, 384, 384, 640, 640, 640, 1152, 1152};
    const int Km[9]  = {64, 256, 256, 512, 512, 512, 1024, 1024, 1024};
    const int off[9] = {0, 64, 320, 576, 1088, 1600, 2112, 3136, 4160};
    const int S[9]   = {192, 384, 384, 640, 640, 640, 1152, 1152, 1024};

    const float* x      = (const float*)d_in[0];
    const float* W_mid  = (const float*)d_in[50];
    const float* b_mid  = (const float*)d_in[51];
    const float* W_head = (const float*)d_in[52];
    const float* b_head = (const float*)d_in[53];

    const size_t M = M_ROWS;

    // -------- common buffers --------
    char* p = (char*)d_ws;
    float* mid    = (float*)p; p += M * 512 * 4;
    float* sbuf   = (float*)p; p += M * 8 * 4;
    float* pooled = (float*)p; p += 128 * 3072 * 4;
    float* biassh = (float*)p; p += 8 * 128 * 4;
    bf16*  hbuf   = (bf16*)p;  p += M * 64 * 2;

    // -------- big-path layout --------
    char* pb = p;
    bf16* aggb = (bf16*)pb; pb += M * 128 * 2;
    bf16* feat = (bf16*)pb; pb += M * 5184 * 2;
    bf16* wshB = (bf16*)pb; pb += (size_t)532480 * 2;    // sum 128*Kh
    bf16* wtoB = (bf16*)pb; pb += (size_t)4014080 * 2;   // sum fo*Ko
    bf16* wtmB = (bf16*)pb; pb += (size_t)512 * 5184 * 2;
    const size_t neededBig = (size_t)(pb - (char*)d_ws);

    // -------- small-path layout --------
    char* ps = p;
    bf16* xA = (bf16*)ps; ps += M * 1152 * 2;
    bf16* xB = (bf16*)ps; ps += M * 1152 * 2;
    bf16* wshS = (bf16*)ps; ps += (size_t)532480 * 2;
    bf16* wtoS = (bf16*)ps; ps += (size_t)4014080 * 2;
    bf16* wtmS = (bf16*)ps; ps += (size_t)512 * 5184 * 2;
    const size_t neededSmall = (size_t)(ps - (char*)d_ws);

    if (ws_size < neededSmall) {
        diag_kernel<<<1, 1, 0, stream>>>((float*)d_out, (float)ws_size);
        return;
    }
    const bool big = (ws_size >= neededBig);

    bf16* wshBase = big ? wshB : wshS;
    bf16* wtoBase = big ? wtoB : wtoS;
    const size_t wshOfs[8] = {0, 8192, 40960, 73728, 139264, 204800,
                              270336, 401408};
    const size_t wtoOfs[8] = {0, 49152, 147456, 344064, 671744, 999424,
                              1654784, 2834432};

    // -------- weight prep (fused) --------
    BiasArgs ba; ShArgs sa; WoArgs wa;
    for (int L = 0; L < 8; ++L) {
        sa.Ws[L] = (const float*)d_in[2 + 6 * L];
        ba.bs[L] = (const float*)d_in[3 + 6 * L];
        sa.Wh[L] = (const float*)d_in[4 + 6 * L];
        ba.bh[L] = (const float*)d_in[5 + 6 * L];
        wa.Wo[L] = (const float*)d_in[6 + 6 * L];
    }
    wprep_sh_all<<<dim3(4, 128, 8), 256, 0, stream>>>(sa, wshBase);
    wprep_t_all<<<dim3(36, 32, 8), dim3(32, 8), 0, stream>>>(
        wa, wtoBase, big ? 1 : 0);
    bias_build_all<<<8, 128, 0, stream>>>(ba, biassh);

    if (big) {
        wprep_mid_big<<<dim3(162, 16), dim3(32, 8), 0, stream>>>(W_mid, wtmB);
        f2b_big<<<(int)(M * 64 / 256), 256, 0, stream>>>(x, feat);

        for (int L = 0; L < 8; ++L) {
            const float* bo = (const float*)d_in[7 + 6 * L];
            // grid: (col tiles, row tiles) -- consecutive blocks share A panel
            mgemm<0><<<dim3(1, 256), 256, 0, stream>>>(
                feat + off[L], 5184, nullptr, 0, 9999,
                wshBase + wshOfs[L], biassh + L * 128, (float*)hbuf, 64, sbuf, Kh[L]);
            knng_kernel<<<(int)(M / 4), 256, 0, stream>>>(
                sbuf, hbuf, aggb, 128, 0, 0);
            mgemm<1><<<dim3(fo[L] / 128, 256), 256, 0, stream>>>(
                feat + off[L], 5184, aggb, 128, fip[L] >> 6,
                wtoBase + wtoOfs[L], bo, (float*)(feat + off[L + 1]), 5184,
                nullptr, Ko[L]);
        }
        mgemm<3><<<dim3(4, 256), 256, 0, stream>>>(
            feat, 5184, nullptr, 0, 9999,
            wtmB, b_mid, mid, 512, nullptr, 5184);
    } else {
        bf16* wtm[9];
        {
            bf16* wp = wtmS;
            for (int i = 0; i < 9; ++i) { wtm[i] = wp; wp += (size_t)512 * Km[i]; }
        }
        wprep_mid_all<<<dim3(162, 16), dim3(32, 8), 0, stream>>>(W_mid, wtm[0]);
        f2b_pad<<<(int)(M * 8 / 256), 256, 0, stream>>>(x, xA);
        init_mid<<<(int)(M * 512 / 256), 256, 0, stream>>>(mid, b_mid);

        bf16* bufs[2] = {xA, xB};
        for (int L = 0; L < 8; ++L) {
            bf16* xin = bufs[L & 1];
            bf16* xout = bufs[(L + 1) & 1];
            const float* bo = (const float*)d_in[7 + 6 * L];
            mgemm<0><<<dim3(1, 256), 256, 0, stream>>>(
                xin, S[L], nullptr, 0, 9999,
                wshBase + wshOfs[L], biassh + L * 128, (float*)hbuf, 64, sbuf, Kh[L]);
            knng_kernel<<<(int)(M / 4), 256, 0, stream>>>(
                sbuf, hbuf, xin, S[L], fi[L], (L == 0) ? 56 : 0);
            mgemm<2><<<dim3(4, 256), 256, 0, stream>>>(
                xin, S[L], nullptr, 0, 9999,
                wtm[L], nullptr, mid, 512, nullptr, Km[L]);
            mgemm<1><<<dim3(fo[L] / 128, 256), 256, 0, stream>>>(
                xin, S[L], nullptr, 0, 9999,
                wtoBase + wtoOfs[L], bo, (float*)xout, S[L + 1], nullptr, Ko[L]);
        }
        mgemm<2><<<dim3(4, 256), 256, 0, stream>>>(
            bufs[0], S[8], nullptr, 0, 9999,
            wtm[8], nullptr, mid, 512, nullptr, Km[8]);
    }

    pool_kernel<<<dim3(GB, 16), 256, 0, stream>>>(mid, pooled);
    head_kernel<<<GB, 128, 0, stream>>>(pooled, W_head, b_head, (float*)d_out);
}